// Round 1
// baseline (95.125 us; speedup 1.0000x reference)
//
#include <hip/hip_runtime.h>
#include <hip/hip_bf16.h>
#include <stdint.h>

#define THRESH_FACTOR 0.05f

typedef __attribute__((ext_vector_type(8))) short short8;
typedef __attribute__((ext_vector_type(4))) float floatx4;

__device__ inline unsigned int bfbits(float f) {
    unsigned int u = __float_as_uint(f);
    return (u + 0x7FFFu + ((u >> 16) & 1u)) >> 16;   // RNE bf16 bits
}

// ---------------- Kernel 1: per-row ternary quantization -----------------
// One block (256 threads) per output row. Produces bf16 ternary weights
// (exact {-1,0,+1}) and per-row scale = mean|w| over kept entries.
__global__ void __launch_bounds__(256) quant_tern(
        const float* __restrict__ W, unsigned short* __restrict__ Wq,
        float* __restrict__ scale, int IN)
{
    const int row = blockIdx.x;
    const int tid = threadIdx.x;
    const int lane = tid & 63;
    const int wid = tid >> 6;
    const float4* wr4 = (const float4*)(W + (size_t)row * IN);
    const int n4 = IN >> 2;

    float s = 0.f;
    for (int i = tid; i < n4; i += 256) {
        float4 v = wr4[i];
        s += fabsf(v.x) + fabsf(v.y) + fabsf(v.z) + fabsf(v.w);
    }
    #pragma unroll
    for (int off = 32; off; off >>= 1) s += __shfl_down(s, off);
    __shared__ float redA[4], redB[4];
    if (lane == 0) redA[wid] = s;
    __syncthreads();
    const float delta = THRESH_FACTOR * (redA[0] + redA[1] + redA[2] + redA[3]) / (float)IN;
    __syncthreads();   // all delta-reads done before redA reuse

    float ks = 0.f, kn = 0.f;
    ushort4* out4 = (ushort4*)(Wq + (size_t)row * IN);
    for (int i = tid; i < n4; i += 256) {
        float4 v = wr4[i];
        ushort4 t;
        float a; unsigned int u;
        a = fabsf(v.x); u = __float_as_uint(v.x);
        if (a > delta) { ks += a; kn += 1.f; t.x = (unsigned short)(0x3F80u | ((u >> 16) & 0x8000u)); } else t.x = 0;
        a = fabsf(v.y); u = __float_as_uint(v.y);
        if (a > delta) { ks += a; kn += 1.f; t.y = (unsigned short)(0x3F80u | ((u >> 16) & 0x8000u)); } else t.y = 0;
        a = fabsf(v.z); u = __float_as_uint(v.z);
        if (a > delta) { ks += a; kn += 1.f; t.z = (unsigned short)(0x3F80u | ((u >> 16) & 0x8000u)); } else t.z = 0;
        a = fabsf(v.w); u = __float_as_uint(v.w);
        if (a > delta) { ks += a; kn += 1.f; t.w = (unsigned short)(0x3F80u | ((u >> 16) & 0x8000u)); } else t.w = 0;
        out4[i] = t;
    }
    #pragma unroll
    for (int off = 32; off; off >>= 1) { ks += __shfl_down(ks, off); kn += __shfl_down(kn, off); }
    if (lane == 0) { redA[wid] = ks; redB[wid] = kn; }
    __syncthreads();
    if (tid == 0) {
        float tks = redA[0] + redA[1] + redA[2] + redA[3];
        float tkn = redB[0] + redB[1] + redB[2] + redB[3];
        scale[row] = tks / fmaxf(tkn, 1.f);
    }
}

// ---------------- Kernel 2: cast x (f32) -> bf16 -----------------
__global__ void __launch_bounds__(256) cast_x(
        const float* __restrict__ X, unsigned short* __restrict__ Xb, int n8)
{
    int idx = blockIdx.x * blockDim.x + threadIdx.x;
    int stride = gridDim.x * blockDim.x;
    const float4* x4 = (const float4*)X;
    uint4* o16 = (uint4*)Xb;
    for (int i = idx; i < n8; i += stride) {
        float4 a = x4[2 * i], b = x4[2 * i + 1];
        uint4 o;
        o.x = bfbits(a.x) | (bfbits(a.y) << 16);
        o.y = bfbits(a.z) | (bfbits(a.w) << 16);
        o.z = bfbits(b.x) | (bfbits(b.y) << 16);
        o.w = bfbits(b.z) | (bfbits(b.w) << 16);
        o16[i] = o;
    }
}

// ---------------- Kernel 3: bf16 MFMA GEMM, C = Xb @ Wq^T * scale + bias ----
// BM=128 BN=64 BK=32; 256 threads = 4 waves (2x2), each wave 64x32 output
// (4x2 fragments of 16x16x32). global_load_lds width-16 staging, linear LDS.
#define BM 128
#define BN 64
#define BKK 32

__global__ void __launch_bounds__(256, 2) gemm_tern(
        const unsigned short* __restrict__ Xb,   // [M][K] bf16 bits
        const unsigned short* __restrict__ Wq,   // [N][K] bf16 bits (ternary)
        const float* __restrict__ scale,         // [N]
        const float* __restrict__ bias,          // [N]
        float* __restrict__ C,                   // [M][N] f32
        int M, int N, int K)
{
    __shared__ __attribute__((aligned(16))) unsigned short As[BM * BKK]; // 8 KB
    __shared__ __attribute__((aligned(16))) unsigned short Bs[BN * BKK]; // 4 KB

    const int tid  = threadIdx.x;
    const int lane = tid & 63;
    const int wid  = tid >> 6;   // 0..3
    const int wr   = wid >> 1;   // 0..1 (M direction)
    const int wc   = wid & 1;    // 0..1 (N direction)

    const int bm0 = blockIdx.x * BM;
    const int bn0 = blockIdx.y * BN;

    floatx4 acc[4][2];
    #pragma unroll
    for (int m = 0; m < 4; ++m)
        #pragma unroll
        for (int n = 0; n < 2; ++n)
            acc[m][n] = (floatx4){0.f, 0.f, 0.f, 0.f};

    // staging coords: wave-call c writes LDS [c*1024B .. +1024B), lane l -> +l*16B
    // slot s = c*64 + lane -> tile row = s>>2, k-chunk = (s&3)*8
    int a_row[2], a_col[2];
    #pragma unroll
    for (int i = 0; i < 2; ++i) {
        int s = (wid * 2 + i) * 64 + lane;
        a_row[i] = s >> 2;
        a_col[i] = (s & 3) * 8;
    }
    const int sb    = wid * 64 + lane;
    const int b_row = sb >> 2;
    const int b_col = (sb & 3) * 8;

    const unsigned short* Ag = Xb + (size_t)bm0 * K;
    const unsigned short* Bg = Wq + (size_t)bn0 * K;

    const int mrow = lane & 15;        // fragment row within 16
    const int kch  = (lane >> 4) * 8;  // fragment k-chunk

    for (int k0 = 0; k0 < K; k0 += BKK) {
        #pragma unroll
        for (int i = 0; i < 2; ++i) {
            __builtin_amdgcn_global_load_lds(
                (const __attribute__((address_space(1))) unsigned int*)(Ag + (size_t)a_row[i] * K + k0 + a_col[i]),
                (__attribute__((address_space(3))) unsigned int*)(&As[(wid * 2 + i) * 512]),
                16, 0, 0);
        }
        __builtin_amdgcn_global_load_lds(
            (const __attribute__((address_space(1))) unsigned int*)(Bg + (size_t)b_row * K + k0 + b_col),
            (__attribute__((address_space(3))) unsigned int*)(&Bs[wid * 512]),
            16, 0, 0);
        __syncthreads();

        short8 af[4], bf[2];
        #pragma unroll
        for (int m = 0; m < 4; ++m)
            af[m] = *(const short8*)&As[(wr * 64 + m * 16 + mrow) * BKK + kch];
        #pragma unroll
        for (int n = 0; n < 2; ++n)
            bf[n] = *(const short8*)&Bs[(wc * 32 + n * 16 + mrow) * BKK + kch];

        #pragma unroll
        for (int m = 0; m < 4; ++m)
            #pragma unroll
            for (int n = 0; n < 2; ++n)
                acc[m][n] = __builtin_amdgcn_mfma_f32_16x16x32_bf16(af[m], bf[n], acc[m][n], 0, 0, 0);
        __syncthreads();
    }

    // epilogue: C[row][col] = acc * scale[col] + bias[col]
    #pragma unroll
    for (int n = 0; n < 2; ++n) {
        int col = bn0 + wc * 32 + n * 16 + (lane & 15);
        float sc = scale[col];
        float bs = bias[col];
        #pragma unroll
        for (int m = 0; m < 4; ++m) {
            int row0 = bm0 + wr * 64 + m * 16 + (lane >> 4) * 4;
            #pragma unroll
            for (int j = 0; j < 4; ++j)
                C[(size_t)(row0 + j) * N + col] = acc[m][n][j] * sc + bs;
        }
    }
}

extern "C" void kernel_launch(void* const* d_in, const int* in_sizes, int n_in,
                              void* d_out, int out_size, void* d_ws, size_t ws_size,
                              hipStream_t stream)
{
    const float* x    = (const float*)d_in[0];
    const float* w    = (const float*)d_in[1];
    const float* bias = (const float*)d_in[2];
    float* out = (float*)d_out;

    const int OUT = in_sizes[2];            // 1024
    const int IN  = in_sizes[1] / OUT;      // 4096
    const int B   = in_sizes[0] / IN;       // 4096

    // workspace layout: x_bf16 [B*IN] | w_tern_bf16 [OUT*IN] | scale [OUT]
    unsigned short* Xb = (unsigned short*)d_ws;
    unsigned short* Wq = Xb + (size_t)B * IN;
    float* scale = (float*)(Wq + (size_t)OUT * IN);

    quant_tern<<<OUT, 256, 0, stream>>>(w, Wq, scale, IN);
    cast_x<<<2048, 256, 0, stream>>>(x, Xb, (B * IN) / 8);
    gemm_tern<<<dim3(B / BM, OUT / BN), 256, 0, stream>>>(Xb, Wq, scale, bias, out, B, OUT, IN);
}

// Round 2
// 89.896 us; speedup vs baseline: 1.0582x; 1.0582x over previous
//
#include <hip/hip_runtime.h>
#include <hip/hip_bf16.h>
#include <stdint.h>

#define THRESH_FACTOR 0.05f

typedef __attribute__((ext_vector_type(8))) short short8;
typedef __attribute__((ext_vector_type(4))) float floatx4;

__device__ inline unsigned int bfbits(float f) {
    unsigned int u = __float_as_uint(f);
    return (u + 0x7FFFu + ((u >> 16) & 1u)) >> 16;   // RNE bf16 bits
}

// ---------------- Kernel 1: per-row ternary quantization -----------------
// One block (256 threads) per output row. Produces bf16 ternary weights
// (exact {-1,0,+1}) in CHUNK-SWIZZLED layout: within each 64-element K-block,
// 16B chunk c is stored at chunk position c ^ (row&7). Also per-row scale.
__global__ void __launch_bounds__(256) quant_tern(
        const float* __restrict__ W, unsigned short* __restrict__ Wq,
        float* __restrict__ scale, int IN)
{
    const int row = blockIdx.x;
    const int tid = threadIdx.x;
    const int lane = tid & 63;
    const int wid = tid >> 6;
    const float4* wr4 = (const float4*)(W + (size_t)row * IN);
    const int n4 = IN >> 2;

    float s = 0.f;
    for (int i = tid; i < n4; i += 256) {
        float4 v = wr4[i];
        s += fabsf(v.x) + fabsf(v.y) + fabsf(v.z) + fabsf(v.w);
    }
    #pragma unroll
    for (int off = 32; off; off >>= 1) s += __shfl_down(s, off);
    __shared__ float redA[4], redB[4];
    if (lane == 0) redA[wid] = s;
    __syncthreads();
    const float delta = THRESH_FACTOR * (redA[0] + redA[1] + redA[2] + redA[3]) / (float)IN;
    __syncthreads();   // all delta-reads done before redA reuse

    float ks = 0.f, kn = 0.f;
    uint4* out16 = (uint4*)(Wq + (size_t)row * IN);   // 16B chunks
    const int n8 = IN >> 3;                            // chunks per row
    for (int i = tid; i < n8; i += 256) {
        float4 v0 = wr4[2 * i], v1 = wr4[2 * i + 1];
        float vs[8] = {v0.x, v0.y, v0.z, v0.w, v1.x, v1.y, v1.z, v1.w};
        unsigned int h[8];
        #pragma unroll
        for (int j = 0; j < 8; ++j) {
            float a = fabsf(vs[j]);
            unsigned int u = __float_as_uint(vs[j]);
            if (a > delta) { ks += a; kn += 1.f; h[j] = 0x3F80u | ((u >> 16) & 0x8000u); }
            else h[j] = 0u;
        }
        uint4 o;
        o.x = h[0] | (h[1] << 16);
        o.y = h[2] | (h[3] << 16);
        o.z = h[4] | (h[5] << 16);
        o.w = h[6] | (h[7] << 16);
        const int oc = (i & ~7) | ((i & 7) ^ (row & 7));   // chunk swizzle
        out16[oc] = o;
    }
    #pragma unroll
    for (int off = 32; off; off >>= 1) { ks += __shfl_down(ks, off); kn += __shfl_down(kn, off); }
    if (lane == 0) { redA[wid] = ks; redB[wid] = kn; }
    __syncthreads();
    if (tid == 0) {
        float tks = redA[0] + redA[1] + redA[2] + redA[3];
        float tkn = redB[0] + redB[1] + redB[2] + redB[3];
        scale[row] = tks / fmaxf(tkn, 1.f);
    }
}

// ---------------- Kernel 2: cast x (f32) -> bf16, chunk-swizzled -----------
__global__ void __launch_bounds__(256) cast_x(
        const float* __restrict__ X, unsigned short* __restrict__ Xb,
        int n16, int cpr)   // n16 = total 16B chunks, cpr = chunks per row (IN/8)
{
    int idx = blockIdx.x * blockDim.x + threadIdx.x;
    int stride = gridDim.x * blockDim.x;
    const float4* x4 = (const float4*)X;
    uint4* o16 = (uint4*)Xb;
    for (int i = idx; i < n16; i += stride) {
        int m = i / cpr;                    // source row
        float4 a = x4[2 * i], b = x4[2 * i + 1];
        uint4 o;
        o.x = bfbits(a.x) | (bfbits(a.y) << 16);
        o.y = bfbits(a.z) | (bfbits(a.w) << 16);
        o.z = bfbits(b.x) | (bfbits(b.y) << 16);
        o.w = bfbits(b.z) | (bfbits(b.w) << 16);
        const int oc = (i & ~7) | ((i & 7) ^ (m & 7));   // chunk swizzle
        o16[oc] = o;
    }
}

// ---------------- Kernel 3: bf16 MFMA GEMM, C = Xb @ Wq^T * scale + bias ----
// BM=BN=128, BK=64. 512 threads = 8 waves (2 M x 4 N), wave tile 64x32,
// frags 4(M) x 2(N) of 16x16x32. Double-buffered LDS, depth-2 counted-vmcnt
// pipeline (never drains vmcnt to 0 mid-loop), raw s_barrier.
// LDS rows are 128B, chunk-XOR-swizzled by producers -> 2-way (free) reads.
#define BM 128
#define BN 128
#define BK 64
#define NT_THREADS 512

__global__ void __launch_bounds__(512, 2) gemm_tern(
        const unsigned short* __restrict__ Xb,   // [M][K] bf16 bits, swizzled
        const unsigned short* __restrict__ Wq,   // [N][K] bf16 bits, swizzled
        const float* __restrict__ scale,         // [N]
        const float* __restrict__ bias,          // [N]
        float* __restrict__ C,                   // [M][N] f32
        int M, int N, int K)
{
    __shared__ __attribute__((aligned(16))) unsigned short As[2][BM * BK]; // 2x16KB
    __shared__ __attribute__((aligned(16))) unsigned short Bs[2][BN * BK]; // 2x16KB

    const int tid  = threadIdx.x;
    const int lane = tid & 63;
    const int wid  = tid >> 6;   // 0..7
    const int wr   = wid >> 2;   // 0..1 (M)
    const int wc   = wid & 3;    // 0..3 (N)

    // XCD-aware bijective swizzle (nwg=256, divisible by 8)
    const int nwg = gridDim.x;
    const int bid = blockIdx.x;
    const int swz = (bid & 7) * (nwg >> 3) + (bid >> 3);
    const int ntn = N / BN;                   // 8
    const int bm0 = (swz / ntn) * BM;
    const int bn0 = (swz % ntn) * BN;

    floatx4 acc[4][2];
    #pragma unroll
    for (int m = 0; m < 4; ++m)
        #pragma unroll
        for (int n = 0; n < 2; ++n)
            acc[m][n] = (floatx4){0.f, 0.f, 0.f, 0.f};

    const unsigned short* Ag = Xb + (size_t)bm0 * K;
    const unsigned short* Bg = Wq + (size_t)bn0 * K;

    // staging: tile = 128 rows x 8 chunks of 16B = 1024 slots; 2 calls/thread
    int s_row[2], s_chk[2];
    #pragma unroll
    for (int c = 0; c < 2; ++c) {
        int slot = c * NT_THREADS + tid;
        s_row[c] = slot >> 3;
        s_chk[c] = slot & 7;
    }

    #define STAGE(buf, k0)                                                         \
        do {                                                                       \
            _Pragma("unroll")                                                      \
            for (int c = 0; c < 2; ++c) {                                          \
                __builtin_amdgcn_global_load_lds(                                  \
                    (const __attribute__((address_space(1))) unsigned int*)        \
                        (Ag + (size_t)s_row[c] * K + (k0) + s_chk[c] * 8),         \
                    (__attribute__((address_space(3))) unsigned int*)              \
                        (&As[buf][(c * NT_THREADS + wid * 64) * 8]),               \
                    16, 0, 0);                                                     \
            }                                                                      \
            _Pragma("unroll")                                                      \
            for (int c = 0; c < 2; ++c) {                                          \
                __builtin_amdgcn_global_load_lds(                                  \
                    (const __attribute__((address_space(1))) unsigned int*)        \
                        (Bg + (size_t)s_row[c] * K + (k0) + s_chk[c] * 8),         \
                    (__attribute__((address_space(3))) unsigned int*)              \
                        (&Bs[buf][(c * NT_THREADS + wid * 64) * 8]),               \
                    16, 0, 0);                                                     \
            }                                                                      \
        } while (0)

    const int NT = K / BK;       // 64
    const int mrow = lane & 15;  // fragment row within 16
    const int kq   = lane >> 4;  // fragment k-quad 0..3

    STAGE(0, 0);
    int cur = 0;

    for (int t = 0; t < NT; ++t) {
        if (t + 1 < NT) {
            STAGE(cur ^ 1, (t + 1) * BK);
            asm volatile("s_waitcnt vmcnt(4)" ::: "memory");  // tile t staged (mine)
        } else {
            asm volatile("s_waitcnt vmcnt(0)" ::: "memory");
        }
        __builtin_amdgcn_s_barrier();                         // tile t staged (all)

        short8 af[2][4], bf[2][2];
        #pragma unroll
        for (int kk = 0; kk < 2; ++kk) {
            #pragma unroll
            for (int m = 0; m < 4; ++m) {
                int r = wr * 64 + m * 16 + mrow;
                int c = kk * 4 + kq;
                af[kk][m] = *(const short8*)&As[cur][r * 64 + ((c ^ (r & 7)) * 8)];
            }
            #pragma unroll
            for (int n = 0; n < 2; ++n) {
                int r = wc * 32 + n * 16 + mrow;
                int c = kk * 4 + kq;
                bf[kk][n] = *(const short8*)&Bs[cur][r * 64 + ((c ^ (r & 7)) * 8)];
            }
        }
        __builtin_amdgcn_s_setprio(1);
        #pragma unroll
        for (int kk = 0; kk < 2; ++kk)
            #pragma unroll
            for (int m = 0; m < 4; ++m)
                #pragma unroll
                for (int n = 0; n < 2; ++n)
                    acc[m][n] = __builtin_amdgcn_mfma_f32_16x16x32_bf16(
                        af[kk][m], bf[kk][n], acc[m][n], 0, 0, 0);
        __builtin_amdgcn_s_setprio(0);
        __builtin_amdgcn_s_barrier();    // all reads of buf `cur` done before restage
        cur ^= 1;
    }

    // epilogue: C[row][col] = acc * scale[col] + bias[col]
    #pragma unroll
    for (int n = 0; n < 2; ++n) {
        int col = bn0 + wc * 32 + n * 16 + mrow;
        float sc = scale[col];
        float bs = bias[col];
        #pragma unroll
        for (int m = 0; m < 4; ++m) {
            int row0 = bm0 + wr * 64 + m * 16 + kq * 4;
            #pragma unroll
            for (int j = 0; j < 4; ++j)
                C[(size_t)(row0 + j) * N + col] = acc[m][n][j] * sc + bs;
        }
    }
    #undef STAGE
}

extern "C" void kernel_launch(void* const* d_in, const int* in_sizes, int n_in,
                              void* d_out, int out_size, void* d_ws, size_t ws_size,
                              hipStream_t stream)
{
    const float* x    = (const float*)d_in[0];
    const float* w    = (const float*)d_in[1];
    const float* bias = (const float*)d_in[2];
    float* out = (float*)d_out;

    const int OUT = in_sizes[2];            // 1024
    const int IN  = in_sizes[1] / OUT;      // 4096
    const int B   = in_sizes[0] / IN;       // 4096

    // workspace layout: x_bf16 [B*IN] | w_tern_bf16 [OUT*IN] | scale [OUT]
    unsigned short* Xb = (unsigned short*)d_ws;
    unsigned short* Wq = Xb + (size_t)B * IN;
    float* scale = (float*)(Wq + (size_t)OUT * IN);

    quant_tern<<<OUT, 256, 0, stream>>>(w, Wq, scale, IN);
    cast_x<<<2048, 256, 0, stream>>>(x, Xb, (B * IN) / 8, IN / 8);
    gemm_tern<<<dim3((B / BM) * (OUT / BN)), NT_THREADS, 0, stream>>>(
        Xb, Wq, scale, bias, out, B, OUT, IN);
}

// Round 3
// 72.767 us; speedup vs baseline: 1.3073x; 1.2354x over previous
//
#include <hip/hip_runtime.h>
#include <hip/hip_bf16.h>
#include <stdint.h>

#define THRESH_FACTOR 0.05f

typedef __attribute__((ext_vector_type(8))) short short8;
typedef __attribute__((ext_vector_type(16))) float f32x16;

__device__ inline unsigned int bfbits(float f) {
    unsigned int u = __float_as_uint(f);
    return (u + 0x7FFFu + ((u >> 16) & 1u)) >> 16;   // RNE bf16 bits
}

// ---------------- Kernel 1: per-row ternary quantization -----------------
// One block (256 threads) per output row. Produces bf16 ternary weights
// (exact {-1,0,+1}) in CHUNK-SWIZZLED layout: within each 64-element K-block,
// 16B chunk c is stored at chunk position c ^ (row&7). Also per-row scale.
__global__ void __launch_bounds__(256) quant_tern(
        const float* __restrict__ W, unsigned short* __restrict__ Wq,
        float* __restrict__ scale, int IN)
{
    const int row = blockIdx.x;
    const int tid = threadIdx.x;
    const int lane = tid & 63;
    const int wid = tid >> 6;
    const float4* wr4 = (const float4*)(W + (size_t)row * IN);
    const int n4 = IN >> 2;

    float s = 0.f;
    for (int i = tid; i < n4; i += 256) {
        float4 v = wr4[i];
        s += fabsf(v.x) + fabsf(v.y) + fabsf(v.z) + fabsf(v.w);
    }
    #pragma unroll
    for (int off = 32; off; off >>= 1) s += __shfl_down(s, off);
    __shared__ float redA[4], redB[4];
    if (lane == 0) redA[wid] = s;
    __syncthreads();
    const float delta = THRESH_FACTOR * (redA[0] + redA[1] + redA[2] + redA[3]) / (float)IN;
    __syncthreads();   // all delta-reads done before redA reuse

    float ks = 0.f, kn = 0.f;
    uint4* out16 = (uint4*)(Wq + (size_t)row * IN);   // 16B chunks
    const int n8 = IN >> 3;                            // chunks per row
    for (int i = tid; i < n8; i += 256) {
        float4 v0 = wr4[2 * i], v1 = wr4[2 * i + 1];
        float vs[8] = {v0.x, v0.y, v0.z, v0.w, v1.x, v1.y, v1.z, v1.w};
        unsigned int h[8];
        #pragma unroll
        for (int j = 0; j < 8; ++j) {
            float a = fabsf(vs[j]);
            unsigned int u = __float_as_uint(vs[j]);
            if (a > delta) { ks += a; kn += 1.f; h[j] = 0x3F80u | ((u >> 16) & 0x8000u); }
            else h[j] = 0u;
        }
        uint4 o;
        o.x = h[0] | (h[1] << 16);
        o.y = h[2] | (h[3] << 16);
        o.z = h[4] | (h[5] << 16);
        o.w = h[6] | (h[7] << 16);
        const int oc = (i & ~7) | ((i & 7) ^ (row & 7));   // chunk swizzle
        out16[oc] = o;
    }
    #pragma unroll
    for (int off = 32; off; off >>= 1) { ks += __shfl_down(ks, off); kn += __shfl_down(kn, off); }
    if (lane == 0) { redA[wid] = ks; redB[wid] = kn; }
    __syncthreads();
    if (tid == 0) {
        float tks = redA[0] + redA[1] + redA[2] + redA[3];
        float tkn = redB[0] + redB[1] + redB[2] + redB[3];
        scale[row] = tks / fmaxf(tkn, 1.f);
    }
}

// ---------------- Kernel 2: cast x (f32) -> bf16, chunk-swizzled -----------
__global__ void __launch_bounds__(256) cast_x(
        const float* __restrict__ X, unsigned short* __restrict__ Xb,
        int n16, int cpr)   // n16 = total 16B chunks, cpr = chunks per row (IN/8)
{
    int idx = blockIdx.x * blockDim.x + threadIdx.x;
    int stride = gridDim.x * blockDim.x;
    const float4* x4 = (const float4*)X;
    uint4* o16 = (uint4*)Xb;
    for (int i = idx; i < n16; i += stride) {
        int m = i / cpr;                    // source row
        float4 a = x4[2 * i], b = x4[2 * i + 1];
        uint4 o;
        o.x = bfbits(a.x) | (bfbits(a.y) << 16);
        o.y = bfbits(a.z) | (bfbits(a.w) << 16);
        o.z = bfbits(b.x) | (bfbits(b.y) << 16);
        o.w = bfbits(b.z) | (bfbits(b.w) << 16);
        const int oc = (i & ~7) | ((i & 7) ^ (m & 7));   // chunk swizzle
        o16[oc] = o;
    }
}

// ---------------- Kernel 3: bf16 MFMA GEMM, C = Xb @ Wq^T * scale + bias ----
// BM=BN=128, BK=128. 512 threads = 8 waves: 2x2 spatial grid of 64x64 wave
// tiles x 2 K-groups (kg owns k[kg*64, kg*64+64) of each step). 32x32x16
// MFMA, 2x2 frags per wave. Double-buffered LDS (128 KB), depth-2
// counted-vmcnt pipeline. Producers chunk-XOR-swizzle -> conflict-free reads.
// Final K-group merge through LDS (aliased over staging buffers).
#define BM 128
#define BN 128
#define BK 128
#define THREADS 512

__global__ void __launch_bounds__(512, 2) gemm_tern(
        const unsigned short* __restrict__ Xb,   // [M][K] bf16 bits, swizzled
        const unsigned short* __restrict__ Wq,   // [N][K] bf16 bits, swizzled
        const float* __restrict__ scale,         // [N]
        const float* __restrict__ bias,          // [N]
        float* __restrict__ C,                   // [M][N] f32
        int M, int N, int K)
{
    __shared__ __attribute__((aligned(16))) union SMem {
        struct { unsigned short A[2][BM * BK]; unsigned short B[2][BN * BK]; } s; // 128 KB
        float merge[4][64 * 64];                                                  // 64 KB
    } u;

    const int tid  = threadIdx.x;
    const int lane = tid & 63;
    const int wid  = tid >> 6;   // 0..7
    const int kg   = wid >> 2;   // K-group 0/1
    const int wq   = wid & 3;    // spatial wave id
    const int wr   = wq >> 1;    // 0..1 (M)
    const int wc   = wq & 1;     // 0..1 (N)

    // XCD-aware bijective swizzle (nwg=256, divisible by 8)
    const int nwg = gridDim.x;
    const int bid = blockIdx.x;
    const int swz = (bid & 7) * (nwg >> 3) + (bid >> 3);
    const int ntn = N / BN;                   // 8
    const int bm0 = (swz / ntn) * BM;
    const int bn0 = (swz % ntn) * BN;

    f32x16 acc[2][2];
    #pragma unroll
    for (int m = 0; m < 2; ++m)
        #pragma unroll
        for (int n = 0; n < 2; ++n)
            #pragma unroll
            for (int r = 0; r < 16; ++r)
                acc[m][n][r] = 0.f;

    const unsigned short* Ag = Xb + (size_t)bm0 * K;
    const unsigned short* Bg = Wq + (size_t)bn0 * K;

    // staging: tile = 128 rows x 16 chunks of 16B = 2048 slots; 4 calls/thread
    int srow[4], schk[4];
    #pragma unroll
    for (int c = 0; c < 4; ++c) {
        int slot = c * THREADS + tid;
        srow[c] = slot >> 4;
        schk[c] = slot & 15;
    }
    const int ldsbase = (tid & ~63) * 8;   // wave-uniform element base (+c*4096)

    #define STAGE(buf, t)                                                          \
        do {                                                                       \
            _Pragma("unroll")                                                      \
            for (int c = 0; c < 4; ++c) {                                          \
                __builtin_amdgcn_global_load_lds(                                  \
                    (const __attribute__((address_space(1))) unsigned int*)        \
                        (Ag + (size_t)srow[c] * K + (size_t)((t) * 16 + schk[c]) * 8), \
                    (__attribute__((address_space(3))) unsigned int*)              \
                        (&u.s.A[buf][c * 4096 + ldsbase]),                         \
                    16, 0, 0);                                                     \
                __builtin_amdgcn_global_load_lds(                                  \
                    (const __attribute__((address_space(1))) unsigned int*)        \
                        (Bg + (size_t)srow[c] * K + (size_t)((t) * 16 + schk[c]) * 8), \
                    (__attribute__((address_space(3))) unsigned int*)              \
                        (&u.s.B[buf][c * 4096 + ldsbase]),                         \
                    16, 0, 0);                                                     \
            }                                                                      \
        } while (0)

    const int NT = K / BK;             // 32
    const int r_a = wr * 64 + (lane & 31);   // A row base (m adds 32)
    const int r_b = wc * 64 + (lane & 31);   // B row base (n adds 32)
    const int khalf = lane >> 5;             // 0/1 (k-chunk half within 16-K)

    STAGE(0, 0);
    int cur = 0;

    for (int t = 0; t < NT; ++t) {
        if (t + 1 < NT) {
            STAGE(cur ^ 1, t + 1);
            asm volatile("s_waitcnt vmcnt(8)" ::: "memory");  // my tile-t loads done
        } else {
            asm volatile("s_waitcnt vmcnt(0)" ::: "memory");
        }
        __builtin_amdgcn_s_barrier();                         // tile t staged (all)

        short8 af[4][2], bf[4][2];
        #pragma unroll
        for (int kk = 0; kk < 4; ++kk) {
            #pragma unroll
            for (int m = 0; m < 2; ++m) {
                int r = r_a + m * 32;
                int chk = kg * 8 + ((kk * 2 + khalf) ^ (r & 7));
                af[kk][m] = *(const short8*)&u.s.A[cur][r * BK + chk * 8];
            }
            #pragma unroll
            for (int n = 0; n < 2; ++n) {
                int r = r_b + n * 32;
                int chk = kg * 8 + ((kk * 2 + khalf) ^ (r & 7));
                bf[kk][n] = *(const short8*)&u.s.B[cur][r * BK + chk * 8];
            }
        }
        __builtin_amdgcn_s_setprio(1);
        #pragma unroll
        for (int kk = 0; kk < 4; ++kk)
            #pragma unroll
            for (int m = 0; m < 2; ++m)
                #pragma unroll
                for (int n = 0; n < 2; ++n)
                    acc[m][n] = __builtin_amdgcn_mfma_f32_32x32x16_bf16(
                        af[kk][m], bf[kk][n], acc[m][n], 0, 0, 0);
        __builtin_amdgcn_s_setprio(0);
        __builtin_amdgcn_s_barrier();    // all reads of buf `cur` done before restage
        cur ^= 1;
    }

    // ---- K-group merge through LDS (aliases staging buffers; loop is done) ----
    if (kg == 1) {
        #pragma unroll
        for (int m = 0; m < 2; ++m)
            #pragma unroll
            for (int n = 0; n < 2; ++n)
                #pragma unroll
                for (int r = 0; r < 16; ++r)
                    u.merge[wq][((m * 2 + n) * 16 + r) * 64 + lane] = acc[m][n][r];
    }
    __syncthreads();
    if (kg == 0) {
        #pragma unroll
        for (int n = 0; n < 2; ++n) {
            int col = bn0 + wc * 64 + n * 32 + (lane & 31);
            float sc = scale[col];
            float bs = bias[col];
            #pragma unroll
            for (int m = 0; m < 2; ++m) {
                #pragma unroll
                for (int r = 0; r < 16; ++r) {
                    float v = acc[m][n][r] + u.merge[wq][((m * 2 + n) * 16 + r) * 64 + lane];
                    int row = bm0 + wr * 64 + m * 32 + (r & 3) + 8 * (r >> 2) + 4 * (lane >> 5);
                    C[(size_t)row * N + col] = v * sc + bs;
                }
            }
        }
    }
    #undef STAGE
}

extern "C" void kernel_launch(void* const* d_in, const int* in_sizes, int n_in,
                              void* d_out, int out_size, void* d_ws, size_t ws_size,
                              hipStream_t stream)
{
    const float* x    = (const float*)d_in[0];
    const float* w    = (const float*)d_in[1];
    const float* bias = (const float*)d_in[2];
    float* out = (float*)d_out;

    const int OUT = in_sizes[2];            // 1024
    const int IN  = in_sizes[1] / OUT;      // 4096
    const int B   = in_sizes[0] / IN;       // 4096

    // workspace layout: x_bf16 [B*IN] | w_tern_bf16 [OUT*IN] | scale [OUT]
    unsigned short* Xb = (unsigned short*)d_ws;
    unsigned short* Wq = Xb + (size_t)B * IN;
    float* scale = (float*)(Wq + (size_t)OUT * IN);

    quant_tern<<<OUT, 256, 0, stream>>>(w, Wq, scale, IN);
    cast_x<<<2048, 256, 0, stream>>>(x, Xb, (B * IN) / 8, IN / 8);
    gemm_tern<<<dim3((B / BM) * (OUT / BN)), THREADS, 0, stream>>>(
        Xb, Wq, scale, bias, out, B, OUT, IN);
}